// Round 1
// baseline (456.965 us; speedup 1.0000x reference)
//
#include <hip/hip_runtime.h>
#include <math.h>

#define PI_F 3.14159265358979323846f

typedef float f4 __attribute__((ext_vector_type(4)));

// ---- output layout (flat float offsets, return order) ----
#define OUT_OUTPUT   0            // (64,4096,4)       = 1,048,576
#define OUT_BLOCKS   1048576      // (64,4096,16,16)   = 67,108,864
#define OUT_MU       68157440     // (64,1,2,1)        = 128
#define OUT_UG       68157568     // (64,1,2)          = 128
#define OUT_THETA    68157696     // (64,2,3)          = 384
// total 68,158,080

// ---- workspace layout (flat float offsets) ----
#define WS_A   0          // per block float4 {v1x, v1y, mu_x, mu_y}      : 262144*4
#define WS_C   1048576    // per block float  {rm1 * block_mean}          : 262144
#define WS_P   1310720    // per workgroup float4 {S0, gS1x, gS1y, 0}     : 16384*4
// total 1,376,256 floats = 5.25 MB

// Kernel 1: stream x -> blocks (transpose via LDS), per-16x16-block moments +
// eigensolve, per-workgroup global-moment partials.
// grid (4 colstrips, 64 rowstrips, 64 images), 256 threads.
__global__ __launch_bounds__(256) void k1_blocks(const float* __restrict__ x,
                                                 float* __restrict__ out,
                                                 float* __restrict__ ws) {
    // 16 image-blocks, each stored as 16 rows x 16 cols; stride 264 (pad 8 floats)
    // gives full-bank coverage for both b128 phases and conflict-free b32 moment reads.
    __shared__ float lds[16 * 264];
    __shared__ float redP[3][16];
    const int t = threadIdx.x;
    const int colstrip = blockIdx.x;   // 0..3  (256 cols each)
    const int rowstrip = blockIdx.y;   // 0..63 (16 rows each)
    const int b = blockIdx.z;          // image

    // ---- Phase A: coalesced read of 16x256 strip into LDS (block-major) ----
    const f4* x4 = reinterpret_cast<const f4*>(x)
                 + (size_t)b * 262144 + (size_t)rowstrip * 4096 + colstrip * 64;
    #pragma unroll
    for (int i = 0; i < 4; ++i) {
        int pos4 = i * 256 + t;          // strip float4 index, row-major
        int row  = pos4 >> 6;            // /64 float4 per row
        int col4 = pos4 & 63;
        f4 v = x4[row * 256 + col4];
        int ib = col4 >> 2;              // image-block within strip (0..15)
        int c4 = (col4 & 3) << 2;        // col within block (0,4,8,12)
        *reinterpret_cast<f4*>(&lds[ib * 264 + row * 16 + c4]) = v;
    }
    __syncthreads();

    // ---- Phase B: coalesced nontemporal write of blocks output (write-once stream) ----
    float* outB = out + OUT_BLOCKS
                + ((size_t)b * 4096 + rowstrip * 64 + colstrip * 16) * 256;
    #pragma unroll
    for (int i = 0; i < 4; ++i) {
        int pos4 = i * 256 + t;
        int ib  = pos4 >> 6;             // block index within strip
        int off = (pos4 & 63) << 2;      // float offset within block (0..252)
        f4 v = *reinterpret_cast<const f4*>(&lds[ib * 264 + off]);
        __builtin_nontemporal_store(v, reinterpret_cast<f4*>(outB) + pos4);
    }

    // ---- Phase C: moments. 16 lanes per image-block, lane = column. ----
    const int ib = t >> 4;   // 0..15
    const int c  = t & 15;
    float s0 = 0.f, s1y = 0.f, s2yy = 0.f;
    #pragma unroll
    for (int r = 0; r < 16; ++r) {
        float v  = lds[ib * 264 + r * 16 + c];
        float rf = (float)r;
        s0   += v;
        s1y  += rf * v;
        s2yy += rf * rf * v;
    }
    float cf   = (float)c;
    float s1x  = cf * s0;
    float s2xx = cf * cf * s0;
    float s2xy = cf * s1y;
    // butterfly reduce across the 16 lanes of this image-block
    #pragma unroll
    for (int m = 1; m <= 8; m <<= 1) {
        s0   += __shfl_xor(s0,   m);
        s1x  += __shfl_xor(s1x,  m);
        s1y  += __shfl_xor(s1y,  m);
        s2xx += __shfl_xor(s2xx, m);
        s2yy += __shfl_xor(s2yy, m);
        s2xy += __shfl_xor(s2xy, m);
    }
    if (c == 0) {
        float denom = s0 + 1e-8f;
        float inv   = 1.0f / denom;
        float mu_x = s1x * inv, mu_y = s1y * inv;
        float cxx = (s2xx - 2.f * mu_x * s1x + mu_x * mu_x * s0) * inv;
        float cyy = (s2yy - 2.f * mu_y * s1y + mu_y * mu_y * s0) * inv;
        float cxy = (s2xy - mu_x * s1y - mu_y * s1x + mu_x * mu_y * s0) * inv;
        float tr  = cxx + cyy;
        float det = cxx * cyy - cxy * cxy;
        float disc = sqrtf(fmaxf(tr * tr - 4.f * det, 0.f));
        float L1 = 0.5f * (tr + disc), L2 = 0.5f * (tr - disc);
        float v1x = L1 - cyy, v1y = cxy;
        float n = fmaxf(sqrtf(v1x * v1x + v1y * v1y), 1e-12f);
        v1x /= n; v1y /= n;
        float rm1 = L1 / L2 - 1.0f;

        int l = rowstrip * 64 + colstrip * 16 + ib;   // block index within image
        size_t gbl = (size_t)b * 4096 + l;
        f4 wa = {v1x, v1y, mu_x, mu_y};
        reinterpret_cast<f4*>(ws + WS_A)[gbl] = wa;
        ws[WS_C + gbl] = rm1 * (s0 * (1.f / 256.f));   // rm1 * block_mean

        float X0 = (float)(colstrip * 256 + ib * 16);
        float Y0 = (float)(rowstrip * 16);
        redP[0][ib] = s0;
        redP[1][ib] = s1x + X0 * s0;
        redP[2][ib] = s1y + Y0 * s0;
    }
    __syncthreads();
    if (t == 0) {
        float S0 = 0.f, GX = 0.f, GY = 0.f;
        #pragma unroll
        for (int i = 0; i < 16; ++i) { S0 += redP[0][i]; GX += redP[1][i]; GY += redP[2][i]; }
        int wg = (b << 8) | (rowstrip << 2) | colstrip;   // image-major partial index
        reinterpret_cast<f4*>(ws + WS_P)[wg] = (f4){S0, GX, GY, 0.f};
    }
}

// Kernel 2 (fused k2+k3+k4): global/per-image first moments from partials, mu,
// conf/orient + full-float4 output write + per-image M reduction + theta.
// grid 64 x 256.
__global__ __launch_bounds__(256) void k23_orient(float* __restrict__ out,
                                                  const float* __restrict__ ws) {
    __shared__ float red[16];
    __shared__ float bc[1];
    const int b = blockIdx.x;
    const int t = threadIdx.x;

    // ---- Phase 0: sum the 16384 workgroup partials (L2-resident, 256 KB) ----
    const f4* wp = reinterpret_cast<const f4*>(ws + WS_P);
    float tS0 = 0.f, iS0 = 0.f, igx = 0.f, igy = 0.f;
    #pragma unroll
    for (int k = 0; k < 64; ++k) {
        f4 v = wp[k * 256 + t];          // iteration k reads image k's 256 partials
        tS0 += v.x;
        if (k == b) { iS0 += v.x; igx += v.y; igy += v.z; }
    }
    #pragma unroll
    for (int m = 1; m <= 32; m <<= 1) {
        tS0 += __shfl_xor(tS0, m);
        iS0 += __shfl_xor(iS0, m);
        igx += __shfl_xor(igx, m);
        igy += __shfl_xor(igy, m);
    }
    const int w = t >> 6;
    if ((t & 63) == 0) { red[w] = tS0; red[4 + w] = iS0; red[8 + w] = igx; red[12 + w] = igy; }
    __syncthreads();
    float mu_x = 0.f, mu_y = 0.f;        // live only in t==0
    if (t == 0) {
        float T  = red[0] + red[1] + red[2] + red[3];
        float S  = red[4] + red[5] + red[6] + red[7];
        float GX = red[8] + red[9] + red[10] + red[11];
        float GY = red[12] + red[13] + red[14] + red[15];
        float inv = 1.0f / (S + 1e-8f);
        mu_x = GX * inv; mu_y = GY * inv;
        out[OUT_MU + b * 2 + 0] = mu_x;
        out[OUT_MU + b * 2 + 1] = mu_y;
        bc[0] = T;
    }
    __syncthreads();
    const float invmean = 67108864.0f / bc[0];   // 1/mean(x), global over batch

    // ---- Phase 1: conf/orient, full-line output write, M accumulation ----
    float m00 = 0.f, m01 = 0.f, m11 = 0.f;
    const f4*    wa   = reinterpret_cast<const f4*>(ws + WS_A) + (size_t)b * 4096;
    const float* wc   = ws + WS_C + (size_t)b * 4096;
    f4*          out4 = reinterpret_cast<f4*>(out + OUT_OUTPUT) + (size_t)b * 4096;
    #pragma unroll
    for (int k = 0; k < 16; ++k) {
        int l = t + k * 256;
        f4 a = wa[l];                                 // {v1x, v1y, mu_x, mu_y}
        float z = wc[l] * invmean;                    // (L1/L2-1)*(bmean/mean)
        float conf = 20.f * (1.f / (1.f + expf(-z)) - 0.5f);
        float ox = a.x * conf, oy = a.y * conf;
        out4[l] = (f4){a.z, a.w, ox, oy};             // one full 16B write per block
        m00 += ox * ox; m01 += ox * oy; m11 += oy * oy;
    }
    #pragma unroll
    for (int m = 1; m <= 32; m <<= 1) {
        m00 += __shfl_xor(m00, m);
        m01 += __shfl_xor(m01, m);
        m11 += __shfl_xor(m11, m);
    }
    if ((t & 63) == 0) { red[w] = m00; red[4 + w] = m01; red[8 + w] = m11; }
    __syncthreads();

    // ---- Phase 2: theta / U_global (fused former k4) ----
    if (t == 0) {
        float M00 = red[0] + red[1] + red[2] + red[3];
        float M01 = red[4] + red[5] + red[6] + red[7];
        float M11 = red[8] + red[9] + red[10] + red[11];
        float T = M00 + M11;
        float D = M00 * M11 - M01 * M01;
        float L1g = 0.5f * (T + sqrtf(fmaxf(T * T - 4.f * D, 0.f)));
        float vx = L1g - M11, vy = M01;
        float n = fmaxf(sqrtf(vx * vx + vy * vy), 1e-12f);
        float Vx = vx / n, Vy = vy / n;
        out[OUT_UG + b * 2 + 0] = Vx;
        out[OUT_UG + b * 2 + 1] = Vy;
        float rot = fmodf(atan2f(Vy, Vx + 1e-4f) + 2.f * PI_F, PI_F);
        float diff = 0.5f * PI_F - rot;
        float cc = cosf(diff), ssn = sinf(diff);
        float mtx = (mu_x * (1.f / 1024.f) - 0.5f) * 2.f;
        float mty = (mu_y * (1.f / 1024.f) - 0.5f) * (-2.f);
        out[OUT_THETA + b * 6 + 0] = cc;
        out[OUT_THETA + b * 6 + 1] = -ssn;
        out[OUT_THETA + b * 6 + 2] = mtx;
        out[OUT_THETA + b * 6 + 3] = ssn;
        out[OUT_THETA + b * 6 + 4] = cc;
        out[OUT_THETA + b * 6 + 5] = mty;
    }
}

extern "C" void kernel_launch(void* const* d_in, const int* in_sizes, int n_in,
                              void* d_out, int out_size, void* d_ws, size_t ws_size,
                              hipStream_t stream) {
    const float* x = (const float*)d_in[0];
    float* out = (float*)d_out;
    float* ws  = (float*)d_ws;
    dim3 g1(4, 64, 64);
    k1_blocks<<<g1, 256, 0, stream>>>(x, out, ws);
    k23_orient<<<64, 256, 0, stream>>>(out, ws);
}

// Round 2
// 442.278 us; speedup vs baseline: 1.0332x; 1.0332x over previous
//
#include <hip/hip_runtime.h>
#include <math.h>

#define PI_F 3.14159265358979323846f

typedef float f4 __attribute__((ext_vector_type(4)));

// ---- output layout (flat float offsets, return order) ----
#define OUT_OUTPUT   0            // (64,4096,4)       = 1,048,576
#define OUT_BLOCKS   1048576      // (64,4096,16,16)   = 67,108,864
#define OUT_MU       68157440     // (64,1,2,1)        = 128
#define OUT_UG       68157568     // (64,1,2)          = 128
#define OUT_THETA    68157696     // (64,2,3)          = 384
// total 68,158,080

// ---- workspace layout (flat float offsets) ----
#define WS_A   0          // per block float4 {v1x, v1y, mu_x, mu_y}  : 262144*4
#define WS_C   1048576    // per block float  {rm1 * block_mean}      : 262144
#define WS_PS  1310720    // per workgroup float  S0                  : 16384
#define WS_PG  1327104    // per workgroup float2 {gS1x, gS1y}        : 16384*2
// total 1,359,872 floats = 5.19 MB

// Kernel 1: stream x -> blocks (transpose via LDS), per-16x16-block moments +
// eigensolve, per-workgroup global-moment partials (SoA).
// grid (4 colstrips, 64 rowstrips, 64 images), 256 threads.
__global__ __launch_bounds__(256) void k1_blocks(const float* __restrict__ x,
                                                 float* __restrict__ out,
                                                 float* __restrict__ ws) {
    // 16 image-blocks, each stored as 16 rows x 16 cols; stride 264 (pad 8 floats)
    // gives full-bank coverage for both b128 phases and conflict-free b32 moment reads.
    __shared__ float lds[16 * 264];
    __shared__ float redP[3][16];
    const int t = threadIdx.x;
    const int colstrip = blockIdx.x;   // 0..3  (256 cols each)
    const int rowstrip = blockIdx.y;   // 0..63 (16 rows each)
    const int b = blockIdx.z;          // image

    // ---- Phase A: coalesced read of 16x256 strip into LDS (block-major) ----
    const f4* x4 = reinterpret_cast<const f4*>(x)
                 + (size_t)b * 262144 + (size_t)rowstrip * 4096 + colstrip * 64;
    #pragma unroll
    for (int i = 0; i < 4; ++i) {
        int pos4 = i * 256 + t;          // strip float4 index, row-major
        int row  = pos4 >> 6;            // /64 float4 per row
        int col4 = pos4 & 63;
        f4 v = x4[row * 256 + col4];
        int ib = col4 >> 2;              // image-block within strip (0..15)
        int c4 = (col4 & 3) << 2;        // col within block (0,4,8,12)
        *reinterpret_cast<f4*>(&lds[ib * 264 + row * 16 + c4]) = v;
    }
    __syncthreads();

    // ---- Phase B: coalesced write of blocks output ----
    float* outB = out + OUT_BLOCKS
                + ((size_t)b * 4096 + rowstrip * 64 + colstrip * 16) * 256;
    #pragma unroll
    for (int i = 0; i < 4; ++i) {
        int pos4 = i * 256 + t;
        int ib  = pos4 >> 6;             // block index within strip
        int off = (pos4 & 63) << 2;      // float offset within block (0..252)
        f4 v = *reinterpret_cast<const f4*>(&lds[ib * 264 + off]);
        reinterpret_cast<f4*>(outB)[pos4] = v;
    }

    // ---- Phase C: moments. 16 lanes per image-block, lane = column. ----
    const int ib = t >> 4;   // 0..15
    const int c  = t & 15;
    float s0 = 0.f, s1y = 0.f, s2yy = 0.f;
    #pragma unroll
    for (int r = 0; r < 16; ++r) {
        float v  = lds[ib * 264 + r * 16 + c];
        float rf = (float)r;
        s0   += v;
        s1y  += rf * v;
        s2yy += rf * rf * v;
    }
    float cf   = (float)c;
    float s1x  = cf * s0;
    float s2xx = cf * cf * s0;
    float s2xy = cf * s1y;
    // butterfly reduce across the 16 lanes of this image-block
    #pragma unroll
    for (int m = 1; m <= 8; m <<= 1) {
        s0   += __shfl_xor(s0,   m);
        s1x  += __shfl_xor(s1x,  m);
        s1y  += __shfl_xor(s1y,  m);
        s2xx += __shfl_xor(s2xx, m);
        s2yy += __shfl_xor(s2yy, m);
        s2xy += __shfl_xor(s2xy, m);
    }
    if (c == 0) {
        float denom = s0 + 1e-8f;
        float inv   = 1.0f / denom;
        float mu_x = s1x * inv, mu_y = s1y * inv;
        float cxx = (s2xx - 2.f * mu_x * s1x + mu_x * mu_x * s0) * inv;
        float cyy = (s2yy - 2.f * mu_y * s1y + mu_y * mu_y * s0) * inv;
        float cxy = (s2xy - mu_x * s1y - mu_y * s1x + mu_x * mu_y * s0) * inv;
        float tr  = cxx + cyy;
        float det = cxx * cyy - cxy * cxy;
        float disc = sqrtf(fmaxf(tr * tr - 4.f * det, 0.f));
        float L1 = 0.5f * (tr + disc), L2 = 0.5f * (tr - disc);
        float v1x = L1 - cyy, v1y = cxy;
        float n = fmaxf(sqrtf(v1x * v1x + v1y * v1y), 1e-12f);
        v1x /= n; v1y /= n;
        float rm1 = L1 / L2 - 1.0f;

        int l = rowstrip * 64 + colstrip * 16 + ib;   // block index within image
        size_t gbl = (size_t)b * 4096 + l;
        f4 wa = {v1x, v1y, mu_x, mu_y};
        reinterpret_cast<f4*>(ws + WS_A)[gbl] = wa;
        ws[WS_C + gbl] = rm1 * (s0 * (1.f / 256.f));   // rm1 * block_mean

        float X0 = (float)(colstrip * 256 + ib * 16);
        float Y0 = (float)(rowstrip * 16);
        redP[0][ib] = s0;
        redP[1][ib] = s1x + X0 * s0;
        redP[2][ib] = s1y + Y0 * s0;
    }
    __syncthreads();
    if (t == 0) {
        float S0 = 0.f, GX = 0.f, GY = 0.f;
        #pragma unroll
        for (int i = 0; i < 16; ++i) { S0 += redP[0][i]; GX += redP[1][i]; GY += redP[2][i]; }
        int wg = (b << 8) | (rowstrip << 2) | colstrip;   // image-major partial index
        ws[WS_PS + wg] = S0;
        reinterpret_cast<float2*>(ws + WS_PG)[wg] = make_float2(GX, GY);
    }
}

// Kernel 2 (fused k2+k3+k4): global/per-image first moments from SoA partials,
// mu, conf/orient + full-float4 output write + per-image M reduction + theta.
// grid 64 x 256.
__global__ __launch_bounds__(256) void k23_orient(float* __restrict__ out,
                                                  const float* __restrict__ ws) {
    __shared__ float red[16];
    __shared__ float bc[1];
    const int b = blockIdx.x;
    const int t = threadIdx.x;

    // ---- Phase 0: global S0 (64 KB broadcast) + own-image partials (3 KB) ----
    const float* ps = ws + WS_PS;
    float tS0 = 0.f;
    #pragma unroll
    for (int k = 0; k < 64; ++k) tS0 += ps[k * 256 + t];   // coalesced 1KB/wave/iter
    float iS0 = ps[b * 256 + t];
    float2 g  = reinterpret_cast<const float2*>(ws + WS_PG)[b * 256 + t];
    float igx = g.x, igy = g.y;
    #pragma unroll
    for (int m = 1; m <= 32; m <<= 1) {
        tS0 += __shfl_xor(tS0, m);
        iS0 += __shfl_xor(iS0, m);
        igx += __shfl_xor(igx, m);
        igy += __shfl_xor(igy, m);
    }
    const int w = t >> 6;
    if ((t & 63) == 0) { red[w] = tS0; red[4 + w] = iS0; red[8 + w] = igx; red[12 + w] = igy; }
    __syncthreads();
    float mu_x = 0.f, mu_y = 0.f;        // live only in t==0
    if (t == 0) {
        float T  = red[0] + red[1] + red[2] + red[3];
        float S  = red[4] + red[5] + red[6] + red[7];
        float GX = red[8] + red[9] + red[10] + red[11];
        float GY = red[12] + red[13] + red[14] + red[15];
        float inv = 1.0f / (S + 1e-8f);
        mu_x = GX * inv; mu_y = GY * inv;
        out[OUT_MU + b * 2 + 0] = mu_x;
        out[OUT_MU + b * 2 + 1] = mu_y;
        bc[0] = T;
    }
    __syncthreads();
    const float invmean = 67108864.0f / bc[0];   // 1/mean(x), global over batch

    // ---- Phase 1: conf/orient, full-line output write, M accumulation ----
    float m00 = 0.f, m01 = 0.f, m11 = 0.f;
    const f4*    wa   = reinterpret_cast<const f4*>(ws + WS_A) + (size_t)b * 4096;
    const float* wc   = ws + WS_C + (size_t)b * 4096;
    f4*          out4 = reinterpret_cast<f4*>(out + OUT_OUTPUT) + (size_t)b * 4096;
    #pragma unroll
    for (int k = 0; k < 16; ++k) {
        int l = t + k * 256;
        f4 a = wa[l];                                 // {v1x, v1y, mu_x, mu_y}
        float z = wc[l] * invmean;                    // (L1/L2-1)*(bmean/mean)
        float conf = 20.f * (1.f / (1.f + expf(-z)) - 0.5f);
        float ox = a.x * conf, oy = a.y * conf;
        out4[l] = (f4){a.z, a.w, ox, oy};             // one full 16B write per block
        m00 += ox * ox; m01 += ox * oy; m11 += oy * oy;
    }
    #pragma unroll
    for (int m = 1; m <= 32; m <<= 1) {
        m00 += __shfl_xor(m00, m);
        m01 += __shfl_xor(m01, m);
        m11 += __shfl_xor(m11, m);
    }
    if ((t & 63) == 0) { red[w] = m00; red[4 + w] = m01; red[8 + w] = m11; }
    __syncthreads();

    // ---- Phase 2: theta / U_global (fused former k4) ----
    if (t == 0) {
        float M00 = red[0] + red[1] + red[2] + red[3];
        float M01 = red[4] + red[5] + red[6] + red[7];
        float M11 = red[8] + red[9] + red[10] + red[11];
        float T = M00 + M11;
        float D = M00 * M11 - M01 * M01;
        float L1g = 0.5f * (T + sqrtf(fmaxf(T * T - 4.f * D, 0.f)));
        float vx = L1g - M11, vy = M01;
        float n = fmaxf(sqrtf(vx * vx + vy * vy), 1e-12f);
        float Vx = vx / n, Vy = vy / n;
        out[OUT_UG + b * 2 + 0] = Vx;
        out[OUT_UG + b * 2 + 1] = Vy;
        float rot = fmodf(atan2f(Vy, Vx + 1e-4f) + 2.f * PI_F, PI_F);
        float diff = 0.5f * PI_F - rot;
        float cc = cosf(diff), ssn = sinf(diff);
        float mtx = (mu_x * (1.f / 1024.f) - 0.5f) * 2.f;
        float mty = (mu_y * (1.f / 1024.f) - 0.5f) * (-2.f);
        out[OUT_THETA + b * 6 + 0] = cc;
        out[OUT_THETA + b * 6 + 1] = -ssn;
        out[OUT_THETA + b * 6 + 2] = mtx;
        out[OUT_THETA + b * 6 + 3] = ssn;
        out[OUT_THETA + b * 6 + 4] = cc;
        out[OUT_THETA + b * 6 + 5] = mty;
    }
}

extern "C" void kernel_launch(void* const* d_in, const int* in_sizes, int n_in,
                              void* d_out, int out_size, void* d_ws, size_t ws_size,
                              hipStream_t stream) {
    const float* x = (const float*)d_in[0];
    float* out = (float*)d_out;
    float* ws  = (float*)d_ws;
    dim3 g1(4, 64, 64);
    k1_blocks<<<g1, 256, 0, stream>>>(x, out, ws);
    k23_orient<<<64, 256, 0, stream>>>(out, ws);
}